// Round 11
// baseline (100.519 us; speedup 1.0000x reference)
//
#include <hip/hip_runtime.h>
#include <hip/hip_fp16.h>

#define IN_F   50000
#define OUT_F  50000
#define NNZ_N  800000
#define BATCH  256
#define ELL_CAP 32
#define OVF_CAP 4096
#define NXCD    8
#define ROWS_PER_SLICE (OUT_F / NXCD)     // 6250, exact
#define BUILD_CHUNK 1024                  // entries per build block

typedef int   i32x4 __attribute__((ext_vector_type(4)));
typedef float f32x4 __attribute__((ext_vector_type(4)));

static constexpr size_t align256(size_t x) { return (x + 255) & ~size_t(255); }

// ---------------- ws layout (int8 ELL path) ----------------
static constexpr size_t OFF_OVFCNT = 0;                                   // int
static constexpr size_t OFF_ECNT   = 256;                                 // OUT_F ints
static constexpr size_t OFF_OVF    = OFF_ECNT + align256(4 * OUT_F);      // OVF_CAP int2
static constexpr size_t OFF_ELL    = OFF_OVF + align256(8 * OVF_CAP);     // OUT_F*ELL_CAP u32
static constexpr size_t OFF_XQ     = OFF_ELL + align256((size_t)4 * OUT_F * ELL_CAP);
static constexpr size_t OFF_SCL    = OFF_XQ + align256((size_t)IN_F * BATCH);
static constexpr size_t OFF_RCV    = OFF_SCL + align256(4 * IN_F);        // NNZ int2
static constexpr size_t WS_PART    = OFF_RCV + align256((size_t)8 * NNZ_N);

// ---------------- CSR fallback ws layout (insurance only) ----------------
static constexpr size_t OFF_FLAG = 0;
static constexpr size_t OFF_CNT  = 256;
static constexpr size_t OFF_PTR  = OFF_CNT + align256(4 * (OUT_F + 1));
static constexpr size_t OFF_CUR  = OFF_PTR + align256(4 * (OUT_F + 1));
static constexpr size_t OFF_COL  = OFF_CUR + align256(4 * OUT_F);
static constexpr size_t OFF_VAL  = OFF_COL + align256(4 * NNZ_N);
static constexpr size_t WS_CSR   = OFF_VAL + align256(4 * NNZ_N);

// ---------------------------------------------------------------------------
__device__ __forceinline__ int detect_is32_inline(const void* p) {
    const unsigned* u = (const unsigned*)p;
    int is32 = 0;
    #pragma unroll
    for (int k = 0; k < 8; ++k) is32 |= (u[2 * k + 1] != 0u);
    return is32;
}

__device__ __forceinline__ int load_index(const void* p, int elem, int is32) {
    if (is32) return ((const int*)p)[elem];
    return (int)((const long long*)p)[elem];
}

#define NORM_BLKS  (NNZ_N / 256)                         // 3125
#define QUANT_BLKS (IN_F / 4)                            // 12500 (4 cols/block)
#define ZERO_BLKS  49                                    // ceil(50000/4/256)
#define NCHUNK     ((NNZ_N + BUILD_CHUNK - 1) / BUILD_CHUNK)  // 782
#define BUILD_BLKS (NCHUNK * NXCD)                       // 6256

// ===========================================================================
// K1 fused (independent read-streams):
//   [0, NORM_BLKS):       indices/values -> rcv[] = (r, u16 c | f16(v)<<16)
//   next QUANT_BLKS:      per-column int8 quant of x (wave per column)
//   next ZERO_BLKS:       zero cnt[] (+ ovf_cnt)
// ===========================================================================
__global__ void norm_quant_kernel(const void* __restrict__ indices,
                                  const float* __restrict__ values,
                                  int2* __restrict__ rcv,
                                  const float* __restrict__ x,
                                  unsigned* __restrict__ xq,
                                  float* __restrict__ scl,
                                  int* __restrict__ cnt,
                                  int* __restrict__ ovf_cnt) {
    int b = blockIdx.x;
    if (b < NORM_BLKS) {
        int i = b * 256 + threadIdx.x;
        int is32 = detect_is32_inline(indices);
        int r = load_index(indices, i, is32);
        int c = load_index(indices, NNZ_N + i, is32);
        unsigned short h = __half_as_ushort(__float2half(values[i]));
        int2 e;
        e.x = r;
        e.y = (int)((unsigned)(c & 0xFFFF) | ((unsigned)h << 16));
        rcv[i] = e;
        return;
    }
    if (b < NORM_BLKS + QUANT_BLKS) {
        int qb = b - NORM_BLKS;
        int wid = threadIdx.x >> 6, lane = threadIdx.x & 63;
        int c = qb * 4 + wid;
        float4 xv = reinterpret_cast<const float4*>(x)[(size_t)c * 64 + lane];
        float m = fmaxf(fmaxf(fabsf(xv.x), fabsf(xv.y)),
                        fmaxf(fabsf(xv.z), fabsf(xv.w)));
        #pragma unroll
        for (int d = 1; d < 64; d <<= 1) m = fmaxf(m, __shfl_xor(m, d, 64));
        float inv = (m > 0.f) ? 127.0f / m : 0.f;
        int q0 = __float2int_rn(xv.x * inv);
        int q1 = __float2int_rn(xv.y * inv);
        int q2 = __float2int_rn(xv.z * inv);
        int q3 = __float2int_rn(xv.w * inv);
        unsigned pk = (unsigned)(q0 & 0xFF) | ((unsigned)(q1 & 0xFF) << 8) |
                      ((unsigned)(q2 & 0xFF) << 16) | ((unsigned)(q3 & 0xFF) << 24);
        xq[(size_t)c * 64 + lane] = pk;
        if (lane == 0) scl[c] = m * (1.0f / 127.0f);
        return;
    }
    int zb = b - NORM_BLKS - QUANT_BLKS;
    int i = zb * 256 + threadIdx.x;
    if (i < OUT_F / 4) reinterpret_cast<int4*>(cnt)[i] = make_int4(0, 0, 0, 0);
    if (zb == 0 && threadIdx.x == 0) *ovf_cnt = 0;
}

// ===========================================================================
// K2: XCD-partitioned ELL build (8 slices, round-8 proven geometry). Block b
// scans nnz chunk (b>>3), claims rows in slice (b&7); each 0.8 MB ELL slice
// stays L2-local under round-robin dispatch. The rcv rescan stream is read
// NON-TEMPORALLY so it does not evict the ELL slice from L2 (the round-9/10
// WRITE_SIZE ~36-45 MB partial-line writeback signature).
// ===========================================================================
__global__ void build_kernel(const int2* __restrict__ rcv,
                             int* __restrict__ cnt,
                             unsigned* __restrict__ ell,
                             int* __restrict__ ovf_cnt,
                             int2* __restrict__ ovf) {
    int slice = blockIdx.x & (NXCD - 1);
    int chunk = blockIdx.x >> 3;
    int rlo = slice * ROWS_PER_SLICE;
    int rhi = rlo + ROWS_PER_SLICE;
    int base = chunk * BUILD_CHUNK + threadIdx.x * 4;
    if (base >= NNZ_N) return;   // NNZ_N % 4 == 0 -> all 4 entries valid
    const i32x4* p = (const i32x4*)(rcv + base);
    i32x4 a  = __builtin_nontemporal_load(p);
    i32x4 b2 = __builtin_nontemporal_load(p + 1);
    int      r[4]  = {a.x, a.z, b2.x, b2.z};
    unsigned cv[4] = {(unsigned)a.y, (unsigned)a.w, (unsigned)b2.y, (unsigned)b2.w};
    #pragma unroll
    for (int k = 0; k < 4; ++k) {
        if (r[k] >= rlo && r[k] < rhi) {
            int pos = atomicAdd(&cnt[r[k]], 1);
            if (pos < ELL_CAP) {
                ell[(size_t)r[k] * ELL_CAP + pos] = cv[k];
            } else {
                int o = atomicAdd(ovf_cnt, 1);
                if (o < OVF_CAP) ovf[o] = make_int2(r[k], (int)cv[k]);
            }
        }
    }
}

// ===========================================================================
// K3: SpMM over int8 x. One wave per row; lane owns 4 batch elems. Before
// the gather loop, the wave bitonic-sorts its row's entries by COLUMN
// (rotated key puts col in the high 16 bits; pad 0xFFFFFFFF sorts last).
// All waves then sweep column space in rough sync -> the instantaneous
// gather working set shrinks to an L2-resident band. Output is stored
// non-temporally so the 51 MB write-once stream doesn't evict xq from L2.
// ===========================================================================
__global__ void spmm_ell_i8_kernel(const unsigned* __restrict__ xq,
                                   const float* __restrict__ scl,
                                   const int* __restrict__ cnt_arr,
                                   const unsigned* __restrict__ ell,
                                   const float* __restrict__ bias,
                                   float* __restrict__ out) {
    int r = blockIdx.x * 4 + (threadIdx.x >> 6);
    int lane = threadIdx.x & 63;

    int cnt = cnt_arr[r];
    if (cnt > ELL_CAP) cnt = ELL_CAP;

    unsigned pe = 0xFFFFFFFFu;
    if (lane < cnt) pe = ell[(size_t)r * ELL_CAP + lane];

    // ---- bitonic sort by column (key = col<<16 | val16; valid col < 65535) ----
    unsigned key = (pe << 16) | (pe >> 16);
    #pragma unroll
    for (int k = 2; k <= 64; k <<= 1) {
        #pragma unroll
        for (int j = k >> 1; j > 0; j >>= 1) {
            unsigned other = __shfl_xor(key, j, 64);
            bool lower = (lane & j) == 0;       // this lane is the low partner
            bool asc   = (lane & k) == 0;       // ascending region
            unsigned mn = (other < key) ? other : key;
            unsigned mx = (other < key) ? key : other;
            key = (lower == asc) ? mn : mx;
        }
    }
    pe = (key << 16) | (key >> 16);

    float bv = bias[r];
    float4 acc = make_float4(bv, bv, bv, bv);

    int j = 0;
    for (; j + 8 <= cnt; j += 8) {
        unsigned g[8]; float v[8];
        #pragma unroll
        for (int k = 0; k < 8; ++k) {
            unsigned e = __shfl(pe, j + k);
            unsigned c = e & 0xFFFFu;
            v[k] = __half2float(__ushort_as_half((unsigned short)(e >> 16))) * scl[c];
            g[k] = xq[(size_t)c * 64 + lane];
        }
        #pragma unroll
        for (int k = 0; k < 8; ++k) {
            acc.x += v[k] * (float)(signed char)(g[k] & 0xFF);
            acc.y += v[k] * (float)(signed char)((g[k] >> 8) & 0xFF);
            acc.z += v[k] * (float)(signed char)((g[k] >> 16) & 0xFF);
            acc.w += v[k] * (float)(signed char)(g[k] >> 24);
        }
    }
    for (; j < cnt; ++j) {
        unsigned e = __shfl(pe, j);
        unsigned c = e & 0xFFFFu;
        float vv = __half2float(__ushort_as_half((unsigned short)(e >> 16))) * scl[c];
        unsigned g = xq[(size_t)c * 64 + lane];
        acc.x += vv * (float)(signed char)(g & 0xFF);
        acc.y += vv * (float)(signed char)((g >> 8) & 0xFF);
        acc.z += vv * (float)(signed char)((g >> 16) & 0xFF);
        acc.w += vv * (float)(signed char)(g >> 24);
    }
    f32x4 o; o.x = acc.x; o.y = acc.y; o.z = acc.z; o.w = acc.w;
    __builtin_nontemporal_store(o, (f32x4*)(out + (size_t)r * BATCH + lane * 4));
}

// K4: apply overflow entries (expected ~0): one wave per entry, strided.
__global__ void ovf_apply_kernel(const int* __restrict__ ovf_cnt,
                                 const int2* __restrict__ ovf,
                                 const unsigned* __restrict__ xq,
                                 const float* __restrict__ scl,
                                 float* __restrict__ out) {
    int n = *ovf_cnt;
    if (n > OVF_CAP) n = OVF_CAP;
    int wave = blockIdx.x * 4 + (threadIdx.x >> 6);
    int lane = threadIdx.x & 63;
    for (int e = wave; e < n; e += 256) {
        int2 pk = ovf[e];
        int r = pk.x;
        unsigned cv = (unsigned)pk.y;
        unsigned c = cv & 0xFFFFu;
        float v = __half2float(__ushort_as_half((unsigned short)(cv >> 16))) * scl[c];
        unsigned g = xq[(size_t)c * 64 + lane];
        float* o = out + (size_t)r * BATCH + lane * 4;
        atomicAdd(o + 0, v * (float)(signed char)(g & 0xFF));
        atomicAdd(o + 1, v * (float)(signed char)((g >> 8) & 0xFF));
        atomicAdd(o + 2, v * (float)(signed char)((g >> 16) & 0xFF));
        atomicAdd(o + 3, v * (float)(signed char)(g >> 24));
    }
}

// ===========================================================================
// CSR fallback path (round-2, known-good; insurance only)
// ===========================================================================
__global__ void detect_idx_kernel(const unsigned int* __restrict__ idx,
                                  int* __restrict__ flag) {
    if (blockIdx.x == 0 && threadIdx.x == 0) {
        int any_nonzero_hi = 0;
        for (int i = 0; i < 64; ++i)
            if (idx[2 * i + 1] != 0u) any_nonzero_hi = 1;
        *flag = any_nonzero_hi;
    }
}

__global__ void hist_kernel(const void* __restrict__ indices,
                            const int* __restrict__ flag,
                            int* __restrict__ cnt) {
    int i = blockIdx.x * blockDim.x + threadIdx.x;
    if (i >= NNZ_N) return;
    int r = load_index(indices, i, *flag);
    atomicAdd(&cnt[r], 1);
}

#define SCAN_BLOCK 1024
__global__ void scan_kernel(const int* __restrict__ cnt, int* __restrict__ ptr, int n) {
    __shared__ int wsum[16];
    __shared__ int carry;
    int tid = threadIdx.x;
    int lane = tid & 63, wid = tid >> 6;
    if (tid == 0) carry = 0;
    __syncthreads();
    for (int base = 0; base < n; base += SCAN_BLOCK) {
        int i = base + tid;
        int v = (i < n) ? cnt[i] : 0;
        int s = v;
        #pragma unroll
        for (int d = 1; d < 64; d <<= 1) {
            int t = __shfl_up(s, d, 64);
            if (lane >= d) s += t;
        }
        if (lane == 63) wsum[wid] = s;
        __syncthreads();
        if (wid == 0 && lane < 16) {
            int wv = wsum[lane];
            #pragma unroll
            for (int d = 1; d < 16; d <<= 1) {
                int t = __shfl_up(wv, d, 64);
                if (lane >= d) wv += t;
            }
            wsum[lane] = wv;
        }
        __syncthreads();
        int waveoff = (wid == 0) ? 0 : wsum[wid - 1];
        if (i < n) ptr[i] = carry + waveoff + s - v;
        __syncthreads();
        if (tid == SCAN_BLOCK - 1) carry += waveoff + s;
        __syncthreads();
    }
    if (tid == 0) ptr[n] = carry;
}

__global__ void scatter_kernel(const void* __restrict__ indices,
                               const float* __restrict__ values,
                               const int* __restrict__ flag,
                               int* __restrict__ cursor,
                               int* __restrict__ csr_col,
                               float* __restrict__ csr_val) {
    int i = blockIdx.x * blockDim.x + threadIdx.x;
    if (i >= NNZ_N) return;
    int is32 = *flag;
    int r = load_index(indices, i, is32);
    int c = load_index(indices, NNZ_N + i, is32);
    int pos = atomicAdd(&cursor[r], 1);
    csr_col[pos] = c;
    csr_val[pos] = values[i];
}

__global__ void spmm_csr_kernel(const float* __restrict__ x,
                                const int* __restrict__ row_ptr,
                                const int* __restrict__ csr_col,
                                const float* __restrict__ csr_val,
                                const float* __restrict__ bias,
                                float* __restrict__ out) {
    int r = blockIdx.x * 4 + (threadIdx.x >> 6);
    int lane = threadIdx.x & 63;
    if (r >= OUT_F) return;
    float bv = bias[r];
    float4 acc = make_float4(bv, bv, bv, bv);
    int start = row_ptr[r], end = row_ptr[r + 1];
    const float4* x4 = reinterpret_cast<const float4*>(x);
    for (int i = start; i < end; ++i) {
        int c = csr_col[i];
        float v = csr_val[i];
        float4 xv = x4[(size_t)c * 64 + lane];
        acc.x += v * xv.x;
        acc.y += v * xv.y;
        acc.z += v * xv.z;
        acc.w += v * xv.w;
    }
    reinterpret_cast<float4*>(out)[(size_t)r * 64 + lane] = acc;
}

// ===========================================================================
extern "C" void kernel_launch(void* const* d_in, const int* in_sizes, int n_in,
                              void* d_out, int out_size, void* d_ws, size_t ws_size,
                              hipStream_t stream) {
    const float* x       = (const float*)d_in[0];
    const void*  indices = d_in[1];
    const float* values  = (const float*)d_in[2];
    const float* bias    = (const float*)d_in[3];
    float* out = (float*)d_out;
    char* ws = (char*)d_ws;

    if (ws_size >= WS_PART) {
        int*      ovf_cnt = (int*)(ws + OFF_OVFCNT);
        int*      cnt     = (int*)(ws + OFF_ECNT);
        int2*     ovf     = (int2*)(ws + OFF_OVF);
        unsigned* ell     = (unsigned*)(ws + OFF_ELL);
        unsigned* xq      = (unsigned*)(ws + OFF_XQ);
        float*    scl     = (float*)(ws + OFF_SCL);
        int2*     rcv     = (int2*)(ws + OFF_RCV);

        norm_quant_kernel<<<NORM_BLKS + QUANT_BLKS + ZERO_BLKS, 256, 0, stream>>>(
            indices, values, rcv, x, xq, scl, cnt, ovf_cnt);

        build_kernel<<<BUILD_BLKS, 256, 0, stream>>>(rcv, cnt, ell, ovf_cnt, ovf);

        spmm_ell_i8_kernel<<<OUT_F / 4, 256, 0, stream>>>(
            xq, scl, cnt, ell, bias, out);

        ovf_apply_kernel<<<64, 256, 0, stream>>>(ovf_cnt, ovf, xq, scl, out);
        return;
    }

    // -------- CSR fallback --------
    int* flag = (int*)(ws + OFF_FLAG);
    detect_idx_kernel<<<1, 64, 0, stream>>>((const unsigned int*)indices, flag);

    int*   row_cnt = (int*)(ws + OFF_CNT);
    int*   row_ptr = (int*)(ws + OFF_PTR);
    int*   cursor  = (int*)(ws + OFF_CUR);
    int*   csr_col = (int*)(ws + OFF_COL);
    float* csr_val = (float*)(ws + OFF_VAL);

    hipMemsetAsync(row_cnt, 0, 4 * (OUT_F + 1), stream);
    hist_kernel<<<(NNZ_N + 255) / 256, 256, 0, stream>>>(indices, flag, row_cnt);
    scan_kernel<<<1, SCAN_BLOCK, 0, stream>>>(row_cnt, row_ptr, OUT_F);
    hipMemcpyAsync(cursor, row_ptr, 4 * OUT_F, hipMemcpyDeviceToDevice, stream);
    scatter_kernel<<<(NNZ_N + 255) / 256, 256, 0, stream>>>(indices, values, flag,
                                                            cursor, csr_col, csr_val);
    spmm_csr_kernel<<<(OUT_F + 3) / 4, 256, 0, stream>>>(x, row_ptr, csr_col, csr_val,
                                                         bias, out);
}

// Round 12
// 97.457 us; speedup vs baseline: 1.0314x; 1.0314x over previous
//
#include <hip/hip_runtime.h>
#include <hip/hip_fp16.h>

#define IN_F   50000
#define OUT_F  50000
#define NNZ_N  800000
#define BATCH  256
#define ELL_CAP 32
#define OVF_CAP 4096
#define NXCD    8
#define ROWS_PER_SLICE (OUT_F / NXCD)     // 6250, exact
#define BIN_CHUNK 1024                    // nnz per bin block
#define NBINBLK ((NNZ_N + BIN_CHUNK - 1) / BIN_CHUNK)   // 782
#define CELL_CAP 256                      // mean 128, +12 sigma
#define CELLS_PER_BUILD 4

typedef float f32x4 __attribute__((ext_vector_type(4)));

static constexpr size_t align256(size_t x) { return (x + 255) & ~size_t(255); }

// ---------------- ws layout ----------------
static constexpr size_t OFF_OVFCNT = 0;                                   // int
static constexpr size_t OFF_ECNT   = 256;                                 // OUT_F ints
static constexpr size_t OFF_OVF    = OFF_ECNT + align256(4 * OUT_F);      // OVF_CAP int2
static constexpr size_t OFF_ELL    = OFF_OVF + align256(8 * OVF_CAP);     // OUT_F*ELL_CAP u32
static constexpr size_t OFF_XQ     = OFF_ELL + align256((size_t)4 * OUT_F * ELL_CAP);
static constexpr size_t OFF_SCL    = OFF_XQ + align256((size_t)IN_F * BATCH);
static constexpr size_t OFF_BCNT   = OFF_SCL + align256(4 * IN_F);        // 8*NBINBLK ints
static constexpr size_t OFF_BIN    = OFF_BCNT + align256(4 * NXCD * NBINBLK);
static constexpr size_t WS_PART    = OFF_BIN + align256((size_t)8 * NXCD * NBINBLK * CELL_CAP);

// ---------------- CSR fallback ws layout (insurance only) ----------------
static constexpr size_t OFF_FLAG = 0;
static constexpr size_t OFF_CNT  = 256;
static constexpr size_t OFF_PTR  = OFF_CNT + align256(4 * (OUT_F + 1));
static constexpr size_t OFF_CUR  = OFF_PTR + align256(4 * (OUT_F + 1));
static constexpr size_t OFF_COL  = OFF_CUR + align256(4 * OUT_F);
static constexpr size_t OFF_VAL  = OFF_COL + align256(4 * NNZ_N);
static constexpr size_t WS_CSR   = OFF_VAL + align256(4 * NNZ_N);

// ---------------------------------------------------------------------------
__device__ __forceinline__ int detect_is32_inline(const void* p) {
    const unsigned* u = (const unsigned*)p;
    int is32 = 0;
    #pragma unroll
    for (int k = 0; k < 8; ++k) is32 |= (u[2 * k + 1] != 0u);
    return is32;
}

__device__ __forceinline__ int load_index(const void* p, int elem, int is32) {
    if (is32) return ((const int*)p)[elem];
    return (int)((const long long*)p)[elem];
}

#define QUANT_BLKS (IN_F / 4)     // 12500 (4 cols/block)
#define ZERO_BLKS  49             // ceil(50000/4/256)
#define BUILD2_BLKS (((NBINBLK + CELLS_PER_BUILD - 1) / CELLS_PER_BUILD) * NXCD)  // 196*8=1568

// ===========================================================================
// K1 fused:
//   [0, NBINBLK):        bin 1024 nnz into 8 per-slice LDS buckets (LDS
//                        atomics only), write each bucket coalesced to its
//                        private (slice, block) cell. No global cursors.
//   next QUANT_BLKS:     per-column int8 quant of x (wave per column)
//   next ZERO_BLKS:      zero cnt[]
// (ovf_cnt zeroed by a 256B memset before this kernel.)
// ===========================================================================
__global__ void bin_quant_kernel(const void* __restrict__ indices,
                                 const float* __restrict__ values,
                                 const float* __restrict__ x,
                                 unsigned* __restrict__ xq,
                                 float* __restrict__ scl,
                                 int* __restrict__ bcnt,
                                 int2* __restrict__ binned,
                                 int* __restrict__ cnt,
                                 int* __restrict__ ovf_cnt,
                                 int2* __restrict__ ovf) {
    int b = blockIdx.x;
    if (b < NBINBLK) {
        __shared__ int  lcnt[NXCD];
        __shared__ int2 lbuf[NXCD][CELL_CAP];
        int tid = threadIdx.x;
        if (tid < NXCD) lcnt[tid] = 0;
        __syncthreads();

        int base = b * BIN_CHUNK + tid * 4;
        if (base < NNZ_N) {   // NNZ_N % 4 == 0 -> all 4 valid when base valid
            int is32 = detect_is32_inline(indices);
            int r[4], c[4];
            if (is32) {
                int4 rr = reinterpret_cast<const int4*>(indices)[base >> 2];
                int4 cc = reinterpret_cast<const int4*>((const int*)indices + NNZ_N)[base >> 2];
                r[0] = rr.x; r[1] = rr.y; r[2] = rr.z; r[3] = rr.w;
                c[0] = cc.x; c[1] = cc.y; c[2] = cc.z; c[3] = cc.w;
            } else {
                const longlong2* rp = reinterpret_cast<const longlong2*>(indices);
                const longlong2* cp = reinterpret_cast<const longlong2*>((const long long*)indices + NNZ_N);
                longlong2 r01 = rp[base >> 1], r23 = rp[(base >> 1) + 1];
                longlong2 c01 = cp[base >> 1], c23 = cp[(base >> 1) + 1];
                r[0] = (int)r01.x; r[1] = (int)r01.y; r[2] = (int)r23.x; r[3] = (int)r23.y;
                c[0] = (int)c01.x; c[1] = (int)c01.y; c[2] = (int)c23.x; c[3] = (int)c23.y;
            }
            float4 vv = reinterpret_cast<const float4*>(values)[base >> 2];
            float v[4] = {vv.x, vv.y, vv.z, vv.w};
            #pragma unroll
            for (int k = 0; k < 4; ++k) {
                unsigned short h = __half_as_ushort(__float2half(v[k]));
                int2 e;
                e.x = r[k];
                e.y = (int)((unsigned)(c[k] & 0xFFFF) | ((unsigned)h << 16));
                int slice = r[k] / ROWS_PER_SLICE;
                int pos = atomicAdd(&lcnt[slice], 1);
                if (pos < CELL_CAP) {
                    lbuf[slice][pos] = e;
                } else {
                    int o = atomicAdd(ovf_cnt, 1);   // ~never (mean 128, cap 256)
                    if (o < OVF_CAP) ovf[o] = e;
                }
            }
        }
        __syncthreads();
        #pragma unroll
        for (int s = 0; s < NXCD; ++s) {
            int n = lcnt[s]; if (n > CELL_CAP) n = CELL_CAP;
            int2* dst = binned + ((size_t)s * NBINBLK + b) * CELL_CAP;
            for (int i = tid; i < n; i += 256) dst[i] = lbuf[s][i];
        }
        if (tid < NXCD) {
            int n = lcnt[tid]; if (n > CELL_CAP) n = CELL_CAP;
            bcnt[tid * NBINBLK + b] = n;
        }
        return;
    }
    b -= NBINBLK;
    if (b < QUANT_BLKS) {
        int wid = threadIdx.x >> 6, lane = threadIdx.x & 63;
        int c = b * 4 + wid;
        float4 xv = reinterpret_cast<const float4*>(x)[(size_t)c * 64 + lane];
        float m = fmaxf(fmaxf(fabsf(xv.x), fabsf(xv.y)),
                        fmaxf(fabsf(xv.z), fabsf(xv.w)));
        #pragma unroll
        for (int d = 1; d < 64; d <<= 1) m = fmaxf(m, __shfl_xor(m, d, 64));
        float inv = (m > 0.f) ? 127.0f / m : 0.f;
        int q0 = __float2int_rn(xv.x * inv);
        int q1 = __float2int_rn(xv.y * inv);
        int q2 = __float2int_rn(xv.z * inv);
        int q3 = __float2int_rn(xv.w * inv);
        unsigned pk = (unsigned)(q0 & 0xFF) | ((unsigned)(q1 & 0xFF) << 8) |
                      ((unsigned)(q2 & 0xFF) << 16) | ((unsigned)(q3 & 0xFF) << 24);
        xq[(size_t)c * 64 + lane] = pk;
        if (lane == 0) scl[c] = m * (1.0f / 127.0f);
        return;
    }
    b -= QUANT_BLKS;
    int i = b * 256 + threadIdx.x;
    if (i < OUT_F / 4) reinterpret_cast<int4*>(cnt)[i] = make_int4(0, 0, 0, 0);
}

// ===========================================================================
// K2: pass-B build. Block b: slice = b&7 (XCD-local ELL slice, proven),
// handles 4 cells of that slice; one thread per entry; folds scl[c] into
// the stored f16 value so the spmm needs no scl access.
// ===========================================================================
__global__ void build2_kernel(const int* __restrict__ bcnt,
                              const int2* __restrict__ binned,
                              const float* __restrict__ scl,
                              int* __restrict__ cnt,
                              unsigned* __restrict__ ell,
                              int* __restrict__ ovf_cnt,
                              int2* __restrict__ ovf) {
    int slice = blockIdx.x & (NXCD - 1);
    int g = blockIdx.x >> 3;
    int tid = threadIdx.x;
    #pragma unroll
    for (int k = 0; k < CELLS_PER_BUILD; ++k) {
        int cell = g * CELLS_PER_BUILD + k;
        if (cell >= NBINBLK) break;
        int n = bcnt[slice * NBINBLK + cell];
        if (tid < n) {
            int2 e = binned[((size_t)slice * NBINBLK + cell) * CELL_CAP + tid];
            int r = e.x;
            unsigned cv = (unsigned)e.y;
            unsigned c = cv & 0xFFFFu;
            float vs = __half2float(__ushort_as_half((unsigned short)(cv >> 16))) * scl[c];
            unsigned h = (unsigned)__half_as_ushort(__float2half(vs));
            int pos = atomicAdd(&cnt[r], 1);
            if (pos < ELL_CAP) {
                ell[(size_t)r * ELL_CAP + pos] = c | (h << 16);
            } else {
                int o = atomicAdd(ovf_cnt, 1);       // ~3-5 rows/call (Poisson-16 tail)
                if (o < OVF_CAP) ovf[o] = make_int2(r, (int)cv);  // raw v; scl in K4
            }
        }
    }
}

// ===========================================================================
// K3: SpMM over int8 x (round-9 form: no sort, no scl — folded in K2).
// One wave per row; lane owns 4 batch elems. Unroll-8. NT store of out.
// ===========================================================================
__global__ void spmm_ell_i8_kernel(const unsigned* __restrict__ xq,
                                   const int* __restrict__ cnt_arr,
                                   const unsigned* __restrict__ ell,
                                   const float* __restrict__ bias,
                                   float* __restrict__ out) {
    int r = blockIdx.x * 4 + (threadIdx.x >> 6);
    int lane = threadIdx.x & 63;

    int cnt = cnt_arr[r];
    if (cnt > ELL_CAP) cnt = ELL_CAP;

    unsigned pe = 0;
    if (lane < cnt) pe = ell[(size_t)r * ELL_CAP + lane];

    float bv = bias[r];
    float4 acc = make_float4(bv, bv, bv, bv);

    int j = 0;
    for (; j + 8 <= cnt; j += 8) {
        unsigned g[8]; float v[8];
        #pragma unroll
        for (int k = 0; k < 8; ++k) {
            unsigned e = __shfl(pe, j + k);
            v[k] = __half2float(__ushort_as_half((unsigned short)(e >> 16)));
            g[k] = xq[(size_t)(e & 0xFFFFu) * 64 + lane];
        }
        #pragma unroll
        for (int k = 0; k < 8; ++k) {
            acc.x += v[k] * (float)(signed char)(g[k] & 0xFF);
            acc.y += v[k] * (float)(signed char)((g[k] >> 8) & 0xFF);
            acc.z += v[k] * (float)(signed char)((g[k] >> 16) & 0xFF);
            acc.w += v[k] * (float)(signed char)(g[k] >> 24);
        }
    }
    for (; j < cnt; ++j) {
        unsigned e = __shfl(pe, j);
        float vv = __half2float(__ushort_as_half((unsigned short)(e >> 16)));
        unsigned g = xq[(size_t)(e & 0xFFFFu) * 64 + lane];
        acc.x += vv * (float)(signed char)(g & 0xFF);
        acc.y += vv * (float)(signed char)((g >> 8) & 0xFF);
        acc.z += vv * (float)(signed char)((g >> 16) & 0xFF);
        acc.w += vv * (float)(signed char)(g >> 24);
    }
    f32x4 o; o.x = acc.x; o.y = acc.y; o.z = acc.z; o.w = acc.w;
    __builtin_nontemporal_store(o, (f32x4*)(out + (size_t)r * BATCH + lane * 4));
}

// K4: apply overflow entries (raw f16(v); multiply by scl here).
__global__ void ovf_apply_kernel(const int* __restrict__ ovf_cnt,
                                 const int2* __restrict__ ovf,
                                 const unsigned* __restrict__ xq,
                                 const float* __restrict__ scl,
                                 float* __restrict__ out) {
    int n = *ovf_cnt;
    if (n > OVF_CAP) n = OVF_CAP;
    int wave = blockIdx.x * 4 + (threadIdx.x >> 6);
    int lane = threadIdx.x & 63;
    for (int e = wave; e < n; e += 256) {
        int2 pk = ovf[e];
        int r = pk.x;
        unsigned cv = (unsigned)pk.y;
        unsigned c = cv & 0xFFFFu;
        float v = __half2float(__ushort_as_half((unsigned short)(cv >> 16))) * scl[c];
        unsigned g = xq[(size_t)c * 64 + lane];
        float* o = out + (size_t)r * BATCH + lane * 4;
        atomicAdd(o + 0, v * (float)(signed char)(g & 0xFF));
        atomicAdd(o + 1, v * (float)(signed char)((g >> 8) & 0xFF));
        atomicAdd(o + 2, v * (float)(signed char)((g >> 16) & 0xFF));
        atomicAdd(o + 3, v * (float)(signed char)(g >> 24));
    }
}

// ===========================================================================
// CSR fallback path (round-2, known-good; insurance only)
// ===========================================================================
__global__ void detect_idx_kernel(const unsigned int* __restrict__ idx,
                                  int* __restrict__ flag) {
    if (blockIdx.x == 0 && threadIdx.x == 0) {
        int any_nonzero_hi = 0;
        for (int i = 0; i < 64; ++i)
            if (idx[2 * i + 1] != 0u) any_nonzero_hi = 1;
        *flag = any_nonzero_hi;
    }
}

__global__ void hist_kernel(const void* __restrict__ indices,
                            const int* __restrict__ flag,
                            int* __restrict__ cnt) {
    int i = blockIdx.x * blockDim.x + threadIdx.x;
    if (i >= NNZ_N) return;
    int r = load_index(indices, i, *flag);
    atomicAdd(&cnt[r], 1);
}

#define SCAN_BLOCK 1024
__global__ void scan_kernel(const int* __restrict__ cnt, int* __restrict__ ptr, int n) {
    __shared__ int wsum[16];
    __shared__ int carry;
    int tid = threadIdx.x;
    int lane = tid & 63, wid = tid >> 6;
    if (tid == 0) carry = 0;
    __syncthreads();
    for (int base = 0; base < n; base += SCAN_BLOCK) {
        int i = base + tid;
        int v = (i < n) ? cnt[i] : 0;
        int s = v;
        #pragma unroll
        for (int d = 1; d < 64; d <<= 1) {
            int t = __shfl_up(s, d, 64);
            if (lane >= d) s += t;
        }
        if (lane == 63) wsum[wid] = s;
        __syncthreads();
        if (wid == 0 && lane < 16) {
            int wv = wsum[lane];
            #pragma unroll
            for (int d = 1; d < 16; d <<= 1) {
                int t = __shfl_up(wv, d, 64);
                if (lane >= d) wv += t;
            }
            wsum[lane] = wv;
        }
        __syncthreads();
        int waveoff = (wid == 0) ? 0 : wsum[wid - 1];
        if (i < n) ptr[i] = carry + waveoff + s - v;
        __syncthreads();
        if (tid == SCAN_BLOCK - 1) carry += waveoff + s;
        __syncthreads();
    }
    if (tid == 0) ptr[n] = carry;
}

__global__ void scatter_kernel(const void* __restrict__ indices,
                               const float* __restrict__ values,
                               const int* __restrict__ flag,
                               int* __restrict__ cursor,
                               int* __restrict__ csr_col,
                               float* __restrict__ csr_val) {
    int i = blockIdx.x * blockDim.x + threadIdx.x;
    if (i >= NNZ_N) return;
    int is32 = *flag;
    int r = load_index(indices, i, is32);
    int c = load_index(indices, NNZ_N + i, is32);
    int pos = atomicAdd(&cursor[r], 1);
    csr_col[pos] = c;
    csr_val[pos] = values[i];
}

__global__ void spmm_csr_kernel(const float* __restrict__ x,
                                const int* __restrict__ row_ptr,
                                const int* __restrict__ csr_col,
                                const float* __restrict__ csr_val,
                                const float* __restrict__ bias,
                                float* __restrict__ out) {
    int r = blockIdx.x * 4 + (threadIdx.x >> 6);
    int lane = threadIdx.x & 63;
    if (r >= OUT_F) return;
    float bv = bias[r];
    float4 acc = make_float4(bv, bv, bv, bv);
    int start = row_ptr[r], end = row_ptr[r + 1];
    const float4* x4 = reinterpret_cast<const float4*>(x);
    for (int i = start; i < end; ++i) {
        int c = csr_col[i];
        float v = csr_val[i];
        float4 xv = x4[(size_t)c * 64 + lane];
        acc.x += v * xv.x;
        acc.y += v * xv.y;
        acc.z += v * xv.z;
        acc.w += v * xv.w;
    }
    reinterpret_cast<float4*>(out)[(size_t)r * 64 + lane] = acc;
}

// ===========================================================================
extern "C" void kernel_launch(void* const* d_in, const int* in_sizes, int n_in,
                              void* d_out, int out_size, void* d_ws, size_t ws_size,
                              hipStream_t stream) {
    const float* x       = (const float*)d_in[0];
    const void*  indices = d_in[1];
    const float* values  = (const float*)d_in[2];
    const float* bias    = (const float*)d_in[3];
    float* out = (float*)d_out;
    char* ws = (char*)d_ws;

    if (ws_size >= WS_PART) {
        int*      ovf_cnt = (int*)(ws + OFF_OVFCNT);
        int*      cnt     = (int*)(ws + OFF_ECNT);
        int2*     ovf     = (int2*)(ws + OFF_OVF);
        unsigned* ell     = (unsigned*)(ws + OFF_ELL);
        unsigned* xq      = (unsigned*)(ws + OFF_XQ);
        float*    scl     = (float*)(ws + OFF_SCL);
        int*      bcnt    = (int*)(ws + OFF_BCNT);
        int2*     binned  = (int2*)(ws + OFF_BIN);

        hipMemsetAsync(ws, 0, 256, stream);   // ovf_cnt

        bin_quant_kernel<<<NBINBLK + QUANT_BLKS + ZERO_BLKS, 256, 0, stream>>>(
            indices, values, x, xq, scl, bcnt, binned, cnt, ovf_cnt, ovf);

        build2_kernel<<<BUILD2_BLKS, 256, 0, stream>>>(
            bcnt, binned, scl, cnt, ell, ovf_cnt, ovf);

        spmm_ell_i8_kernel<<<OUT_F / 4, 256, 0, stream>>>(
            xq, cnt, ell, bias, out);

        ovf_apply_kernel<<<64, 256, 0, stream>>>(ovf_cnt, ovf, xq, scl, out);
        return;
    }

    // -------- CSR fallback --------
    int* flag = (int*)(ws + OFF_FLAG);
    detect_idx_kernel<<<1, 64, 0, stream>>>((const unsigned int*)indices, flag);

    int*   row_cnt = (int*)(ws + OFF_CNT);
    int*   row_ptr = (int*)(ws + OFF_PTR);
    int*   cursor  = (int*)(ws + OFF_CUR);
    int*   csr_col = (int*)(ws + OFF_COL);
    float* csr_val = (float*)(ws + OFF_VAL);

    hipMemsetAsync(row_cnt, 0, 4 * (OUT_F + 1), stream);
    hist_kernel<<<(NNZ_N + 255) / 256, 256, 0, stream>>>(indices, flag, row_cnt);
    scan_kernel<<<1, SCAN_BLOCK, 0, stream>>>(row_cnt, row_ptr, OUT_F);
    hipMemcpyAsync(cursor, row_ptr, 4 * OUT_F, hipMemcpyDeviceToDevice, stream);
    scatter_kernel<<<(NNZ_N + 255) / 256, 256, 0, stream>>>(indices, values, flag,
                                                            cursor, csr_col, csr_val);
    spmm_csr_kernel<<<(OUT_F + 3) / 4, 256, 0, stream>>>(x, row_ptr, csr_col, csr_val,
                                                         bias, out);
}

// Round 13
// 91.790 us; speedup vs baseline: 1.0951x; 1.0617x over previous
//
#include <hip/hip_runtime.h>
#include <hip/hip_fp16.h>

#define IN_F   50000
#define OUT_F  50000
#define NNZ_N  800000
#define BATCH  256
#define ELL_CAP 32
#define OVF_CAP 4096
#define NXCD    8
#define ROWS_PER_SLICE (OUT_F / NXCD)     // 6250, exact
#define BIN_CHUNK 1024                    // nnz per bin block
#define NBINBLK ((NNZ_N + BIN_CHUNK - 1) / BIN_CHUNK)   // 782
#define CELL_CAP 256                      // mean 128, +12 sigma
#define CELLS_PER_BUILD 4

typedef float f32x4 __attribute__((ext_vector_type(4)));

static constexpr size_t align256(size_t x) { return (x + 255) & ~size_t(255); }

// ---------------- ws layout ----------------
static constexpr size_t OFF_OVFCNT = 0;                                   // int
static constexpr size_t OFF_ECNT   = 256;                                 // OUT_F ints
static constexpr size_t OFF_OVF    = OFF_ECNT + align256(4 * OUT_F);      // OVF_CAP int2
static constexpr size_t OFF_ELL    = OFF_OVF + align256(8 * OVF_CAP);     // OUT_F*ELL_CAP u32
static constexpr size_t OFF_XQ     = OFF_ELL + align256((size_t)4 * OUT_F * ELL_CAP);
static constexpr size_t OFF_SCL    = OFF_XQ + align256((size_t)IN_F * BATCH);
static constexpr size_t OFF_BCNT   = OFF_SCL + align256(4 * IN_F);        // 8*NBINBLK ints
static constexpr size_t OFF_BIN    = OFF_BCNT + align256(4 * NXCD * NBINBLK);
static constexpr size_t WS_PART    = OFF_BIN + align256((size_t)8 * NXCD * NBINBLK * CELL_CAP);

// ---------------- CSR fallback ws layout (insurance only) ----------------
static constexpr size_t OFF_FLAG = 0;
static constexpr size_t OFF_CNT  = 256;
static constexpr size_t OFF_PTR  = OFF_CNT + align256(4 * (OUT_F + 1));
static constexpr size_t OFF_CUR  = OFF_PTR + align256(4 * (OUT_F + 1));
static constexpr size_t OFF_COL  = OFF_CUR + align256(4 * OUT_F);
static constexpr size_t OFF_VAL  = OFF_COL + align256(4 * NNZ_N);
static constexpr size_t WS_CSR   = OFF_VAL + align256(4 * NNZ_N);

// ---------------------------------------------------------------------------
__device__ __forceinline__ int detect_is32_inline(const void* p) {
    const unsigned* u = (const unsigned*)p;
    int is32 = 0;
    #pragma unroll
    for (int k = 0; k < 8; ++k) is32 |= (u[2 * k + 1] != 0u);
    return is32;
}

__device__ __forceinline__ int load_index(const void* p, int elem, int is32) {
    if (is32) return ((const int*)p)[elem];
    return (int)((const long long*)p)[elem];
}

#define QUANT_BLKS (IN_F / 4)     // 12500 (4 cols/block)
#define ZERO_BLKS  49             // ceil(50000/4/256)
#define BUILD2_BLKS (((NBINBLK + CELLS_PER_BUILD - 1) / CELLS_PER_BUILD) * NXCD)  // 196*8=1568

// ===========================================================================
// K1 fused (NO host-side memset anywhere — the runtime's tiny fillBuffer
// dispatch costs ~40us per graph replay, round-12 post-mortem):
//   [0, NBINBLK):        bin 1024 nnz into 8 per-slice LDS buckets (LDS
//                        atomics only), write each bucket coalesced to its
//                        private (slice, block) cell. No global cursors.
//   next QUANT_BLKS:     per-column int8 quant of x (wave per column)
//   next ZERO_BLKS:      zero cnt[] + ovf_cnt
// (bin cell overflow is a +12-sigma event on fixed data; its ovf write
//  effectively never executes, so the in-kernel ovf_cnt zero is safe.)
// ===========================================================================
__global__ void bin_quant_kernel(const void* __restrict__ indices,
                                 const float* __restrict__ values,
                                 const float* __restrict__ x,
                                 unsigned* __restrict__ xq,
                                 float* __restrict__ scl,
                                 int* __restrict__ bcnt,
                                 int2* __restrict__ binned,
                                 int* __restrict__ cnt,
                                 int* __restrict__ ovf_cnt,
                                 int2* __restrict__ ovf) {
    int b = blockIdx.x;
    if (b < NBINBLK) {
        __shared__ int  lcnt[NXCD];
        __shared__ int2 lbuf[NXCD][CELL_CAP];
        int tid = threadIdx.x;
        if (tid < NXCD) lcnt[tid] = 0;
        __syncthreads();

        int base = b * BIN_CHUNK + tid * 4;
        if (base < NNZ_N) {   // NNZ_N % 4 == 0 -> all 4 valid when base valid
            int is32 = detect_is32_inline(indices);
            int r[4], c[4];
            if (is32) {
                int4 rr = reinterpret_cast<const int4*>(indices)[base >> 2];
                int4 cc = reinterpret_cast<const int4*>((const int*)indices + NNZ_N)[base >> 2];
                r[0] = rr.x; r[1] = rr.y; r[2] = rr.z; r[3] = rr.w;
                c[0] = cc.x; c[1] = cc.y; c[2] = cc.z; c[3] = cc.w;
            } else {
                const longlong2* rp = reinterpret_cast<const longlong2*>(indices);
                const longlong2* cp = reinterpret_cast<const longlong2*>((const long long*)indices + NNZ_N);
                longlong2 r01 = rp[base >> 1], r23 = rp[(base >> 1) + 1];
                longlong2 c01 = cp[base >> 1], c23 = cp[(base >> 1) + 1];
                r[0] = (int)r01.x; r[1] = (int)r01.y; r[2] = (int)r23.x; r[3] = (int)r23.y;
                c[0] = (int)c01.x; c[1] = (int)c01.y; c[2] = (int)c23.x; c[3] = (int)c23.y;
            }
            float4 vv = reinterpret_cast<const float4*>(values)[base >> 2];
            float v[4] = {vv.x, vv.y, vv.z, vv.w};
            #pragma unroll
            for (int k = 0; k < 4; ++k) {
                unsigned short h = __half_as_ushort(__float2half(v[k]));
                int2 e;
                e.x = r[k];
                e.y = (int)((unsigned)(c[k] & 0xFFFF) | ((unsigned)h << 16));
                int slice = r[k] / ROWS_PER_SLICE;
                int pos = atomicAdd(&lcnt[slice], 1);
                if (pos < CELL_CAP) {
                    lbuf[slice][pos] = e;
                } else {
                    int o = atomicAdd(ovf_cnt, 1);   // ~never (mean 128, cap 256)
                    if (o < OVF_CAP) ovf[o] = e;
                }
            }
        }
        __syncthreads();
        #pragma unroll
        for (int s = 0; s < NXCD; ++s) {
            int n = lcnt[s]; if (n > CELL_CAP) n = CELL_CAP;
            int2* dst = binned + ((size_t)s * NBINBLK + b) * CELL_CAP;
            for (int i = tid; i < n; i += 256) dst[i] = lbuf[s][i];
        }
        if (tid < NXCD) {
            int n = lcnt[tid]; if (n > CELL_CAP) n = CELL_CAP;
            bcnt[tid * NBINBLK + b] = n;
        }
        return;
    }
    b -= NBINBLK;
    if (b < QUANT_BLKS) {
        int wid = threadIdx.x >> 6, lane = threadIdx.x & 63;
        int c = b * 4 + wid;
        float4 xv = reinterpret_cast<const float4*>(x)[(size_t)c * 64 + lane];
        float m = fmaxf(fmaxf(fabsf(xv.x), fabsf(xv.y)),
                        fmaxf(fabsf(xv.z), fabsf(xv.w)));
        #pragma unroll
        for (int d = 1; d < 64; d <<= 1) m = fmaxf(m, __shfl_xor(m, d, 64));
        float inv = (m > 0.f) ? 127.0f / m : 0.f;
        int q0 = __float2int_rn(xv.x * inv);
        int q1 = __float2int_rn(xv.y * inv);
        int q2 = __float2int_rn(xv.z * inv);
        int q3 = __float2int_rn(xv.w * inv);
        unsigned pk = (unsigned)(q0 & 0xFF) | ((unsigned)(q1 & 0xFF) << 8) |
                      ((unsigned)(q2 & 0xFF) << 16) | ((unsigned)(q3 & 0xFF) << 24);
        xq[(size_t)c * 64 + lane] = pk;
        if (lane == 0) scl[c] = m * (1.0f / 127.0f);
        return;
    }
    b -= QUANT_BLKS;
    int i = b * 256 + threadIdx.x;
    if (i < OUT_F / 4) reinterpret_cast<int4*>(cnt)[i] = make_int4(0, 0, 0, 0);
    if (b == 0 && threadIdx.x == 0) *ovf_cnt = 0;
}

// ===========================================================================
// K2: pass-B build. Block b: slice = b&7 (XCD-local ELL slice, proven),
// handles 4 cells of that slice; one thread per entry; folds scl[c] into
// the stored f16 value so the spmm needs no scl access.
// ===========================================================================
__global__ void build2_kernel(const int* __restrict__ bcnt,
                              const int2* __restrict__ binned,
                              const float* __restrict__ scl,
                              int* __restrict__ cnt,
                              unsigned* __restrict__ ell,
                              int* __restrict__ ovf_cnt,
                              int2* __restrict__ ovf) {
    int slice = blockIdx.x & (NXCD - 1);
    int g = blockIdx.x >> 3;
    int tid = threadIdx.x;
    #pragma unroll
    for (int k = 0; k < CELLS_PER_BUILD; ++k) {
        int cell = g * CELLS_PER_BUILD + k;
        if (cell >= NBINBLK) break;
        int n = bcnt[slice * NBINBLK + cell];
        if (tid < n) {
            int2 e = binned[((size_t)slice * NBINBLK + cell) * CELL_CAP + tid];
            int r = e.x;
            unsigned cv = (unsigned)e.y;
            unsigned c = cv & 0xFFFFu;
            float vs = __half2float(__ushort_as_half((unsigned short)(cv >> 16))) * scl[c];
            unsigned h = (unsigned)__half_as_ushort(__float2half(vs));
            int pos = atomicAdd(&cnt[r], 1);
            if (pos < ELL_CAP) {
                ell[(size_t)r * ELL_CAP + pos] = c | (h << 16);
            } else {
                int o = atomicAdd(ovf_cnt, 1);       // ~3-5 rows/call (Poisson-16 tail)
                if (o < OVF_CAP) ovf[o] = make_int2(r, (int)cv);  // raw v; scl in K4
            }
        }
    }
}

// ===========================================================================
// K3: SpMM over int8 x (no sort, no scl — folded in K2). One wave per row;
// lane owns 4 batch elems. Unroll-8. NT store of out.
// ===========================================================================
__global__ void spmm_ell_i8_kernel(const unsigned* __restrict__ xq,
                                   const int* __restrict__ cnt_arr,
                                   const unsigned* __restrict__ ell,
                                   const float* __restrict__ bias,
                                   float* __restrict__ out) {
    int r = blockIdx.x * 4 + (threadIdx.x >> 6);
    int lane = threadIdx.x & 63;

    int cnt = cnt_arr[r];
    if (cnt > ELL_CAP) cnt = ELL_CAP;

    unsigned pe = 0;
    if (lane < cnt) pe = ell[(size_t)r * ELL_CAP + lane];

    float bv = bias[r];
    float4 acc = make_float4(bv, bv, bv, bv);

    int j = 0;
    for (; j + 8 <= cnt; j += 8) {
        unsigned g[8]; float v[8];
        #pragma unroll
        for (int k = 0; k < 8; ++k) {
            unsigned e = __shfl(pe, j + k);
            v[k] = __half2float(__ushort_as_half((unsigned short)(e >> 16)));
            g[k] = xq[(size_t)(e & 0xFFFFu) * 64 + lane];
        }
        #pragma unroll
        for (int k = 0; k < 8; ++k) {
            acc.x += v[k] * (float)(signed char)(g[k] & 0xFF);
            acc.y += v[k] * (float)(signed char)((g[k] >> 8) & 0xFF);
            acc.z += v[k] * (float)(signed char)((g[k] >> 16) & 0xFF);
            acc.w += v[k] * (float)(signed char)(g[k] >> 24);
        }
    }
    for (; j < cnt; ++j) {
        unsigned e = __shfl(pe, j);
        float vv = __half2float(__ushort_as_half((unsigned short)(e >> 16)));
        unsigned g = xq[(size_t)(e & 0xFFFFu) * 64 + lane];
        acc.x += vv * (float)(signed char)(g & 0xFF);
        acc.y += vv * (float)(signed char)((g >> 8) & 0xFF);
        acc.z += vv * (float)(signed char)((g >> 16) & 0xFF);
        acc.w += vv * (float)(signed char)(g >> 24);
    }
    f32x4 o; o.x = acc.x; o.y = acc.y; o.z = acc.z; o.w = acc.w;
    __builtin_nontemporal_store(o, (f32x4*)(out + (size_t)r * BATCH + lane * 4));
}

// K4: apply overflow entries (raw f16(v); multiply by scl here).
__global__ void ovf_apply_kernel(const int* __restrict__ ovf_cnt,
                                 const int2* __restrict__ ovf,
                                 const unsigned* __restrict__ xq,
                                 const float* __restrict__ scl,
                                 float* __restrict__ out) {
    int n = *ovf_cnt;
    if (n > OVF_CAP) n = OVF_CAP;
    int wave = blockIdx.x * 4 + (threadIdx.x >> 6);
    int lane = threadIdx.x & 63;
    for (int e = wave; e < n; e += 256) {
        int2 pk = ovf[e];
        int r = pk.x;
        unsigned cv = (unsigned)pk.y;
        unsigned c = cv & 0xFFFFu;
        float v = __half2float(__ushort_as_half((unsigned short)(cv >> 16))) * scl[c];
        unsigned g = xq[(size_t)c * 64 + lane];
        float* o = out + (size_t)r * BATCH + lane * 4;
        atomicAdd(o + 0, v * (float)(signed char)(g & 0xFF));
        atomicAdd(o + 1, v * (float)(signed char)((g >> 8) & 0xFF));
        atomicAdd(o + 2, v * (float)(signed char)((g >> 16) & 0xFF));
        atomicAdd(o + 3, v * (float)(signed char)(g >> 24));
    }
}

// ===========================================================================
// CSR fallback path (round-2, known-good; insurance only)
// ===========================================================================
__global__ void detect_idx_kernel(const unsigned int* __restrict__ idx,
                                  int* __restrict__ flag) {
    if (blockIdx.x == 0 && threadIdx.x == 0) {
        int any_nonzero_hi = 0;
        for (int i = 0; i < 64; ++i)
            if (idx[2 * i + 1] != 0u) any_nonzero_hi = 1;
        *flag = any_nonzero_hi;
    }
}

__global__ void hist_kernel(const void* __restrict__ indices,
                            const int* __restrict__ flag,
                            int* __restrict__ cnt) {
    int i = blockIdx.x * blockDim.x + threadIdx.x;
    if (i >= NNZ_N) return;
    int r = load_index(indices, i, *flag);
    atomicAdd(&cnt[r], 1);
}

#define SCAN_BLOCK 1024
__global__ void scan_kernel(const int* __restrict__ cnt, int* __restrict__ ptr, int n) {
    __shared__ int wsum[16];
    __shared__ int carry;
    int tid = threadIdx.x;
    int lane = tid & 63, wid = tid >> 6;
    if (tid == 0) carry = 0;
    __syncthreads();
    for (int base = 0; base < n; base += SCAN_BLOCK) {
        int i = base + tid;
        int v = (i < n) ? cnt[i] : 0;
        int s = v;
        #pragma unroll
        for (int d = 1; d < 64; d <<= 1) {
            int t = __shfl_up(s, d, 64);
            if (lane >= d) s += t;
        }
        if (lane == 63) wsum[wid] = s;
        __syncthreads();
        if (wid == 0 && lane < 16) {
            int wv = wsum[lane];
            #pragma unroll
            for (int d = 1; d < 16; d <<= 1) {
                int t = __shfl_up(wv, d, 64);
                if (lane >= d) wv += t;
            }
            wsum[lane] = wv;
        }
        __syncthreads();
        int waveoff = (wid == 0) ? 0 : wsum[wid - 1];
        if (i < n) ptr[i] = carry + waveoff + s - v;
        __syncthreads();
        if (tid == SCAN_BLOCK - 1) carry += waveoff + s;
        __syncthreads();
    }
    if (tid == 0) ptr[n] = carry;
}

__global__ void scatter_kernel(const void* __restrict__ indices,
                               const float* __restrict__ values,
                               const int* __restrict__ flag,
                               int* __restrict__ cursor,
                               int* __restrict__ csr_col,
                               float* __restrict__ csr_val) {
    int i = blockIdx.x * blockDim.x + threadIdx.x;
    if (i >= NNZ_N) return;
    int is32 = *flag;
    int r = load_index(indices, i, is32);
    int c = load_index(indices, NNZ_N + i, is32);
    int pos = atomicAdd(&cursor[r], 1);
    csr_col[pos] = c;
    csr_val[pos] = values[i];
}

__global__ void spmm_csr_kernel(const float* __restrict__ x,
                                const int* __restrict__ row_ptr,
                                const int* __restrict__ csr_col,
                                const float* __restrict__ csr_val,
                                const float* __restrict__ bias,
                                float* __restrict__ out) {
    int r = blockIdx.x * 4 + (threadIdx.x >> 6);
    int lane = threadIdx.x & 63;
    if (r >= OUT_F) return;
    float bv = bias[r];
    float4 acc = make_float4(bv, bv, bv, bv);
    int start = row_ptr[r], end = row_ptr[r + 1];
    const float4* x4 = reinterpret_cast<const float4*>(x);
    for (int i = start; i < end; ++i) {
        int c = csr_col[i];
        float v = csr_val[i];
        float4 xv = x4[(size_t)c * 64 + lane];
        acc.x += v * xv.x;
        acc.y += v * xv.y;
        acc.z += v * xv.z;
        acc.w += v * xv.w;
    }
    reinterpret_cast<float4*>(out)[(size_t)r * 64 + lane] = acc;
}

// ===========================================================================
extern "C" void kernel_launch(void* const* d_in, const int* in_sizes, int n_in,
                              void* d_out, int out_size, void* d_ws, size_t ws_size,
                              hipStream_t stream) {
    const float* x       = (const float*)d_in[0];
    const void*  indices = d_in[1];
    const float* values  = (const float*)d_in[2];
    const float* bias    = (const float*)d_in[3];
    float* out = (float*)d_out;
    char* ws = (char*)d_ws;

    if (ws_size >= WS_PART) {
        int*      ovf_cnt = (int*)(ws + OFF_OVFCNT);
        int*      cnt     = (int*)(ws + OFF_ECNT);
        int2*     ovf     = (int2*)(ws + OFF_OVF);
        unsigned* ell     = (unsigned*)(ws + OFF_ELL);
        unsigned* xq      = (unsigned*)(ws + OFF_XQ);
        float*    scl     = (float*)(ws + OFF_SCL);
        int*      bcnt    = (int*)(ws + OFF_BCNT);
        int2*     binned  = (int2*)(ws + OFF_BIN);

        bin_quant_kernel<<<NBINBLK + QUANT_BLKS + ZERO_BLKS, 256, 0, stream>>>(
            indices, values, x, xq, scl, bcnt, binned, cnt, ovf_cnt, ovf);

        build2_kernel<<<BUILD2_BLKS, 256, 0, stream>>>(
            bcnt, binned, scl, cnt, ell, ovf_cnt, ovf);

        spmm_ell_i8_kernel<<<OUT_F / 4, 256, 0, stream>>>(
            xq, cnt, ell, bias, out);

        ovf_apply_kernel<<<64, 256, 0, stream>>>(ovf_cnt, ovf, xq, scl, out);
        return;
    }

    // -------- CSR fallback --------
    int* flag = (int*)(ws + OFF_FLAG);
    detect_idx_kernel<<<1, 64, 0, stream>>>((const unsigned int*)indices, flag);

    int*   row_cnt = (int*)(ws + OFF_CNT);
    int*   row_ptr = (int*)(ws + OFF_PTR);
    int*   cursor  = (int*)(ws + OFF_CUR);
    int*   csr_col = (int*)(ws + OFF_COL);
    float* csr_val = (float*)(ws + OFF_VAL);

    hipMemsetAsync(row_cnt, 0, 4 * (OUT_F + 1), stream);
    hist_kernel<<<(NNZ_N + 255) / 256, 256, 0, stream>>>(indices, flag, row_cnt);
    scan_kernel<<<1, SCAN_BLOCK, 0, stream>>>(row_cnt, row_ptr, OUT_F);
    hipMemcpyAsync(cursor, row_ptr, 4 * OUT_F, hipMemcpyDeviceToDevice, stream);
    scatter_kernel<<<(NNZ_N + 255) / 256, 256, 0, stream>>>(indices, values, flag,
                                                            cursor, csr_col, csr_val);
    spmm_csr_kernel<<<(OUT_F + 3) / 4, 256, 0, stream>>>(x, row_ptr, csr_col, csr_val,
                                                         bias, out);
}